// Round 2
// baseline (1815.194 us; speedup 1.0000x reference)
//
#include <hip/hip_runtime.h>
#include <cmath>

// Problem constants
#define BB 128
#define MM 64
#define DD 64
#define PP 1024
#define AN 21
#define NPAIR 2016            // M*(M-1)/2
#define PT 8                  // pairs per wave-tile (8 to keep VGPR <= 128)
#define TILES_PER_B (NPAIR / PT)        // 252
#define TOTAL_TILES (BB * TILES_PER_B)  // 32256

__device__ __forceinline__ float gelu_exact(float x) {
    // exact GELU (matches approximate=False): 0.5*x*(1+erf(x/sqrt(2)))
    return 0.5f * x * (1.0f + erff(x * 0.70710678118654752f));
}

// ---------------------------------------------------------------------------
// Kernel 1: e = pos_table[pos] + aa_table[aa];  u = e @ W1[:64], v = e @ W1[64:]
// Also zeroes the output diagonal (never written by the pair kernel).
// One wave per (b, m). Grid = B*M/4 blocks of 256 threads (4 waves).
// ---------------------------------------------------------------------------
__global__ __launch_bounds__(256) void k_embed_uv(
    const int* __restrict__ positions, const int* __restrict__ amino,
    const float* __restrict__ pos_table, const float* __restrict__ aa_table,
    const float* __restrict__ W1,
    float* __restrict__ u, float* __restrict__ v, float* __restrict__ out)
{
    __shared__ __align__(16) float es[4][DD];
    const int wave = threadIdx.x >> 6;
    const int lane = threadIdx.x & 63;
    const int idx = blockIdx.x * 4 + wave;   // b*M + m  (grid sized exactly)

    int p = positions[idx];
    p = p < 0 ? 0 : (p > PP - 1 ? PP - 1 : p);
    int a = amino[idx];
    a = a < 0 ? 0 : (a > AN - 1 ? AN - 1 : a);

    const float e = pos_table[p * DD + lane] + aa_table[a * DD + lane];
    es[wave][lane] = e;
    // wave-synchronous LDS: ensure write visible before cross-lane reads
    asm volatile("s_waitcnt lgkmcnt(0)" ::: "memory");

    float uacc = 0.0f, vacc = 0.0f;
#pragma unroll
    for (int k = 0; k < DD; ++k) {
        const float ek = es[wave][k];              // broadcast read
        uacc = fmaf(ek, W1[k * DD + lane], uacc);        // W1 rows 0..63
        vacc = fmaf(ek, W1[(DD + k) * DD + lane], vacc); // W1 rows 64..127
    }
    u[idx * DD + lane] = uacc;
    v[idx * DD + lane] = vacc;

    if (lane == 0) {
        const int b = idx >> 6, m = idx & 63;
        out[b * MM * MM + m * MM + m] = 0.0f;      // diagonal
    }
}

// ---------------------------------------------------------------------------
// Kernel 2: for each pair (i<j): h1 = gelu(u_i + v_j + b1);
//           h2 = gelu(h1 @ W2 + b2); s = h2 . W3 + b3;
//           out[b,i,j] = out[b,j,i] = s.
// One wave per 8-pair tile; lane = output feature. W2 column (64 f32) in
// VGPRs, h1 staged in per-wave LDS, broadcast-read as float4 (uniform addr
// -> single-bank broadcast, no conflict).
// __launch_bounds__(256, 4): force <=128 VGPR, 4 waves/SIMD. PT=8 keeps the
// live set (w2c[64] + acc[8] + gelu temps) under that cap -- PT=16 at 256
// VGPR spilled 3.7 GB/dispatch to scratch in round 1.
// ---------------------------------------------------------------------------
__global__ __launch_bounds__(256, 4) void k_pair_mlp(
    const float* __restrict__ u, const float* __restrict__ v,
    const float* __restrict__ W2, const float* __restrict__ b1,
    const float* __restrict__ b2, const float* __restrict__ W3,
    const float* __restrict__ b3, float* __restrict__ out)
{
    __shared__ __align__(16) float h1s[4][PT][DD];
    const int wave = threadIdx.x >> 6;
    const int lane = threadIdx.x & 63;

    // Per-lane constants: column lane of W2, biases, W3 (hoisted, amortized
    // over the grid-stride tile loop)
    float w2c[DD];
#pragma unroll
    for (int k = 0; k < DD; ++k) w2c[k] = W2[k * DD + lane];
    const float b1l = b1[lane];
    const float b2l = b2[lane];
    const float w3l = W3[lane];
    const float b3s = b3[0];

    const int gwave = blockIdx.x * 4 + wave;
    const int nw = gridDim.x * 4;

    for (int tile = gwave; tile < TOTAL_TILES; tile += nw) {
        const int b = tile / TILES_PER_B;
        const int t0 = (tile - b * TILES_PER_B) * PT;

        // decode first pair index: j such that j(j-1)/2 <= t0 < j(j+1)/2
        int j0 = (int)((1.0f + sqrtf(1.0f + 8.0f * (float)t0)) * 0.5f);
        if (j0 * (j0 - 1) / 2 > t0) --j0;
        if (j0 * (j0 + 1) / 2 <= t0) ++j0;
        int i0 = t0 - j0 * (j0 - 1) / 2;

        const float* __restrict__ ub = u + b * (MM * DD);
        const float* __restrict__ vb = v + b * (MM * DD);

        // ----- layer 1: h1 for PT pairs into LDS -----
        {
            int i = i0, j = j0;
#pragma unroll
            for (int pp = 0; pp < PT; ++pp) {
                const float x = ub[i * DD + lane] + vb[j * DD + lane] + b1l;
                h1s[wave][pp][lane] = gelu_exact(x);
                if (++i == j) { i = 0; ++j; }
            }
        }
        asm volatile("s_waitcnt lgkmcnt(0)" ::: "memory");

        // ----- layer 2: acc[pp] = b2 + h1[pp] @ W2[:,lane] -----
        float acc[PT];
#pragma unroll
        for (int pp = 0; pp < PT; ++pp) acc[pp] = b2l;
#pragma unroll
        for (int k = 0; k < DD; k += 4) {
#pragma unroll
            for (int pp = 0; pp < PT; ++pp) {
                const float4 h4 = *reinterpret_cast<const float4*>(&h1s[wave][pp][k]);
                acc[pp] = fmaf(h4.x, w2c[k + 0], acc[pp]);
                acc[pp] = fmaf(h4.y, w2c[k + 1], acc[pp]);
                acc[pp] = fmaf(h4.z, w2c[k + 2], acc[pp]);
                acc[pp] = fmaf(h4.w, w2c[k + 3], acc[pp]);
            }
        }

        // ----- layer 3: gelu, dot with W3, wave-reduce, mirrored write -----
        float* __restrict__ ob = out + b * (MM * MM);
        {
            int i = i0, j = j0;
#pragma unroll
            for (int pp = 0; pp < PT; ++pp) {
                float g = gelu_exact(acc[pp]) * w3l;
#pragma unroll
                for (int off = 32; off >= 1; off >>= 1)
                    g += __shfl_xor(g, off, 64);
                if (lane == 0) {
                    const float s = g + b3s;
                    ob[i * MM + j] = s;
                    ob[j * MM + i] = s;
                }
                if (++i == j) { i = 0; ++j; }
            }
        }
    }
}

extern "C" void kernel_launch(void* const* d_in, const int* in_sizes, int n_in,
                              void* d_out, int out_size, void* d_ws, size_t ws_size,
                              hipStream_t stream) {
    const int*   positions = (const int*)  d_in[0];
    const int*   amino     = (const int*)  d_in[1];
    const float* pos_table = (const float*)d_in[2];
    const float* aa_table  = (const float*)d_in[3];
    const float* W1        = (const float*)d_in[4];
    const float* b1        = (const float*)d_in[5];
    const float* W2        = (const float*)d_in[6];
    const float* b2        = (const float*)d_in[7];
    const float* W3        = (const float*)d_in[8];
    const float* b3        = (const float*)d_in[9];
    float* out = (float*)d_out;

    float* u = (float*)d_ws;                  // [B*M, 64]  (2 MB)
    float* v = u + (size_t)BB * MM * DD;      // [B*M, 64]  (2 MB)

    // Kernel 1: B*M = 8192 waves -> 2048 blocks of 4 waves
    k_embed_uv<<<2048, 256, 0, stream>>>(positions, amino, pos_table, aa_table,
                                         W1, u, v, out);
    // Kernel 2: 32256 tiles over 2016 blocks (8064 waves, ~4 tiles each)
    k_pair_mlp<<<2016, 256, 0, stream>>>(u, v, W2, b1, b2, W3, b3, out);
}

// Round 3
// 61.091 us; speedup vs baseline: 29.7128x; 29.7128x over previous
//
#include <hip/hip_runtime.h>
#include <cmath>

// Problem constants
#define BB 128
#define MM 64
#define DD 64
#define PP 1024
#define AN 21
#define NPAIR 2016            // M*(M-1)/2
#define PT 16                 // pairs per wave-tile = MFMA M dim
#define TILES_PER_B (NPAIR / PT)        // 126
#define TOTAL_TILES (BB * TILES_PER_B)  // 16128

typedef __attribute__((ext_vector_type(8))) short bf16x8;   // 8 bf16 = 4 VGPRs
typedef __attribute__((ext_vector_type(4))) float f32x4;    // MFMA C/D

__device__ __forceinline__ float gelu_exact(float x) {
    // exact GELU (matches approximate=False): 0.5*x*(1+erf(x/sqrt(2)))
    return 0.5f * x * (1.0f + erff(x * 0.70710678118654752f));
}

// RNE float -> bf16 bits (values are finite; no NaN handling needed)
__device__ __forceinline__ unsigned short f2bf(float x) {
    union { float f; unsigned u; } c; c.f = x;
    unsigned r = c.u + 0x7fffu + ((c.u >> 16) & 1u);
    return (unsigned short)(r >> 16);
}

// t -> (i, j), i < j, t = j(j-1)/2 + i
__device__ __forceinline__ void pair_decode(int t, int& i, int& j) {
    int jj = (int)((1.0f + sqrtf(1.0f + 8.0f * (float)t)) * 0.5f);
    if (jj * (jj - 1) / 2 > t) --jj;
    if (jj * (jj + 1) / 2 <= t) ++jj;
    i = t - jj * (jj - 1) / 2;
    j = jj;
}

// ---------------------------------------------------------------------------
// Kernel 0: W2T[out][k] = bf16(W2[k][out])  (4096 elems, trivial)
// ---------------------------------------------------------------------------
__global__ __launch_bounds__(256) void k_prep_w2t(
    const float* __restrict__ W2, unsigned short* __restrict__ w2t)
{
    const int n = blockIdx.x * 256 + threadIdx.x;   // grid = 16 blocks
    const int kk = n >> 6, oo = n & 63;
    w2t[oo * DD + kk] = f2bf(W2[n]);
}

// ---------------------------------------------------------------------------
// Kernel 1: e = pos_table[pos] + aa_table[aa];  u = e @ W1[:64], v = e @ W1[64:]
// W1 (32 KB) staged in block LDS (4 waves share -> 4x less L2 traffic).
// Also zeroes the output diagonal. One wave per (b, m). 2048 blocks x 256.
// ---------------------------------------------------------------------------
__global__ __launch_bounds__(256) void k_embed_uv(
    const int* __restrict__ positions, const int* __restrict__ amino,
    const float* __restrict__ pos_table, const float* __restrict__ aa_table,
    const float* __restrict__ W1,
    float* __restrict__ u, float* __restrict__ v, float* __restrict__ out)
{
    __shared__ __align__(16) float w1s[2 * DD * DD];   // 32 KB, [k][out] layout
    __shared__ __align__(16) float es[4][DD];
    const int wave = threadIdx.x >> 6;
    const int lane = threadIdx.x & 63;

    // cooperative W1 load: 2048 float4 over 256 threads
    {
        const float4* W14 = (const float4*)W1;
        float4* w1s4 = (float4*)w1s;
#pragma unroll
        for (int it = 0; it < 8; ++it)
            w1s4[it * 256 + threadIdx.x] = W14[it * 256 + threadIdx.x];
    }
    __syncthreads();

    const int idx = blockIdx.x * 4 + wave;   // b*M + m (grid sized exactly)
    int p = positions[idx];
    p = p < 0 ? 0 : (p > PP - 1 ? PP - 1 : p);
    int a = amino[idx];
    a = a < 0 ? 0 : (a > AN - 1 ? AN - 1 : a);

    const float e = pos_table[p * DD + lane] + aa_table[a * DD + lane];
    es[wave][lane] = e;
    asm volatile("s_waitcnt lgkmcnt(0)" ::: "memory");  // wave-local visibility

    float uacc = 0.0f, vacc = 0.0f;
#pragma unroll
    for (int k = 0; k < DD; ++k) {
        const float ek = es[wave][k];                    // broadcast read (free)
        uacc = fmaf(ek, w1s[k * DD + lane], uacc);       // rows 0..63
        vacc = fmaf(ek, w1s[(DD + k) * DD + lane], vacc);// rows 64..127
    }
    u[idx * DD + lane] = uacc;
    v[idx * DD + lane] = vacc;

    if (lane == 0) {
        const int b = idx >> 6, m = idx & 63;
        out[b * MM * MM + m * MM + m] = 0.0f;            // diagonal
    }
}

// ---------------------------------------------------------------------------
// Kernel 2: one wave per 16-pair MFMA tile.
// Layer 1: lane (g = l>>4, r = l&15) computes h1[pair=r][k=kh*32+g*8+e]
//          = gelu(u_i[k] + v_j[k] + b1[k]) directly into its own A-fragment
//          (bf16, in-register; no LDS, no barrier).
// Layer 2: 8x mfma_f32_16x16x32_bf16 (2 k-halves x 4 out-col blocks);
//          B-frags from pre-transposed bf16 W2T, hoisted (32 VGPRs total).
// Layer 3: C/D layout col=l&15, row=(l>>4)*4+reg (m89-verified);
//          gelu + W3 dot + shfl_xor(1,2,4,8) reduce over 16-lane col group;
//          lane r==0 of each g writes 4 mirrored pairs.
// No __launch_bounds__ waves arg: round 2's (256,4) forced VGPR=64 and
// re-spilled (w2c[64] couldn't fit). Live set now ~116 VGPR, no spill.
// ---------------------------------------------------------------------------
__global__ __launch_bounds__(256) void k_pair_mfma(
    const float* __restrict__ u, const float* __restrict__ v,
    const unsigned short* __restrict__ w2t,
    const float* __restrict__ b1, const float* __restrict__ b2,
    const float* __restrict__ W3, const float* __restrict__ b3,
    float* __restrict__ out)
{
    const int lane = threadIdx.x & 63;
    const int wave = threadIdx.x >> 6;
    const int r = lane & 15;        // A row = pair-in-tile; also C col = out feature
    const int g = lane >> 4;        // k-group

    // ---- hoisted per-lane constants ----
    // B fragments: lane holds W2[k = kh*32+g*8+e][n = cb*16+r]
    bf16x8 bfr[2][4];
#pragma unroll
    for (int kh = 0; kh < 2; ++kh)
#pragma unroll
        for (int cb = 0; cb < 4; ++cb)
            bfr[kh][cb] = *(const bf16x8*)(w2t + ((cb * 16 + r) * DD + kh * 32 + g * 8));

    // b1 fragment: b1[kh*32 + g*8 + e]
    float b1f[2][8];
#pragma unroll
    for (int kh = 0; kh < 2; ++kh) {
        const float4 lo = *(const float4*)(b1 + kh * 32 + g * 8);
        const float4 hi = *(const float4*)(b1 + kh * 32 + g * 8 + 4);
        b1f[kh][0] = lo.x; b1f[kh][1] = lo.y; b1f[kh][2] = lo.z; b1f[kh][3] = lo.w;
        b1f[kh][4] = hi.x; b1f[kh][5] = hi.y; b1f[kh][6] = hi.z; b1f[kh][7] = hi.w;
    }
    // b2 / W3 fragments: col = cb*16 + r
    float b2f[4], w3f[4];
#pragma unroll
    for (int cb = 0; cb < 4; ++cb) {
        b2f[cb] = b2[cb * 16 + r];
        w3f[cb] = W3[cb * 16 + r];
    }
    const float b3s = b3[0];

    const int tile = blockIdx.x * 4 + wave;          // grid sized exactly
    const int b = tile / TILES_PER_B;
    const int t0 = (tile - b * TILES_PER_B) * PT;

    // ---- layer 1: build A fragments in-register ----
    int i, j;
    pair_decode(t0 + r, i, j);
    const float* __restrict__ up = u + (b * MM + i) * DD;
    const float* __restrict__ vp = v + (b * MM + j) * DD;

    bf16x8 afr[2];
#pragma unroll
    for (int kh = 0; kh < 2; ++kh) {
        const int koff = kh * 32 + g * 8;
        const float4 u0 = *(const float4*)(up + koff);
        const float4 u1 = *(const float4*)(up + koff + 4);
        const float4 v0 = *(const float4*)(vp + koff);
        const float4 v1 = *(const float4*)(vp + koff + 4);
        float x[8];
        x[0] = u0.x + v0.x; x[1] = u0.y + v0.y; x[2] = u0.z + v0.z; x[3] = u0.w + v0.w;
        x[4] = u1.x + v1.x; x[5] = u1.y + v1.y; x[6] = u1.z + v1.z; x[7] = u1.w + v1.w;
#pragma unroll
        for (int e = 0; e < 8; ++e)
            afr[kh][e] = (short)f2bf(gelu_exact(x[e] + b1f[kh][e]));
    }

    // ---- layer 2: 8 MFMAs, accumulate over k-halves ----
    f32x4 acc[4];
#pragma unroll
    for (int cb = 0; cb < 4; ++cb) {
        f32x4 z = {0.0f, 0.0f, 0.0f, 0.0f};
        z = __builtin_amdgcn_mfma_f32_16x16x32_bf16(afr[0], bfr[0][cb], z, 0, 0, 0);
        acc[cb] = __builtin_amdgcn_mfma_f32_16x16x32_bf16(afr[1], bfr[1][cb], z, 0, 0, 0);
    }

    // ---- layer 3: gelu, W3 dot, reduce over col group, mirrored store ----
    float part[4];
#pragma unroll
    for (int reg = 0; reg < 4; ++reg) {
        float s = 0.0f;
#pragma unroll
        for (int cb = 0; cb < 4; ++cb)
            s = fmaf(gelu_exact(acc[cb][reg] + b2f[cb]), w3f[cb], s);
        // sum over the 16 lanes sharing this g (cols 0..15 of each block)
        s += __shfl_xor(s, 1, 64);
        s += __shfl_xor(s, 2, 64);
        s += __shfl_xor(s, 4, 64);
        s += __shfl_xor(s, 8, 64);
        part[reg] = s;
    }

    if (r == 0) {                      // 4 active lanes (one per g)
        float* __restrict__ ob = out + b * (MM * MM);
#pragma unroll
        for (int reg = 0; reg < 4; ++reg) {
            const int p = g * 4 + reg;               // C row = pair index
            int i2, j2;
            pair_decode(t0 + p, i2, j2);
            const float sc = part[reg] + b3s;
            ob[i2 * MM + j2] = sc;
            ob[j2 * MM + i2] = sc;
        }
    }
}

extern "C" void kernel_launch(void* const* d_in, const int* in_sizes, int n_in,
                              void* d_out, int out_size, void* d_ws, size_t ws_size,
                              hipStream_t stream) {
    const int*   positions = (const int*)  d_in[0];
    const int*   amino     = (const int*)  d_in[1];
    const float* pos_table = (const float*)d_in[2];
    const float* aa_table  = (const float*)d_in[3];
    const float* W1        = (const float*)d_in[4];
    const float* b1        = (const float*)d_in[5];
    const float* W2        = (const float*)d_in[6];
    const float* b2        = (const float*)d_in[7];
    const float* W3        = (const float*)d_in[8];
    const float* b3        = (const float*)d_in[9];
    float* out = (float*)d_out;

    float* u = (float*)d_ws;                              // [B*M, 64]  (2 MB)
    float* v = u + (size_t)BB * MM * DD;                  // [B*M, 64]  (2 MB)
    unsigned short* w2t = (unsigned short*)(v + (size_t)BB * MM * DD);  // 8 KB bf16

    // K0: W2 -> bf16 transposed (4096 elems)
    k_prep_w2t<<<16, 256, 0, stream>>>(W2, w2t);
    // K1: B*M = 8192 waves -> 2048 blocks of 4 waves
    k_embed_uv<<<2048, 256, 0, stream>>>(positions, amino, pos_table, aa_table,
                                         W1, u, v, out);
    // K2: 16128 tiles -> 4032 blocks of 4 waves, one 16-pair MFMA tile each
    k_pair_mfma<<<4032, 256, 0, stream>>>(u, v, w2t, b1, b2, W3, b3, out);
}

// Round 4
// 43.362 us; speedup vs baseline: 41.8616x; 1.4089x over previous
//
#include <hip/hip_runtime.h>
#include <cmath>

// Problem constants
#define BB 128
#define MM 64
#define DD 64
#define PP 1024
#define AN 21
#define NPAIR 2016            // M*(M-1)/2
#define PT 16                 // pairs per wave-tile = MFMA M dim
#define TILES_PER_B (NPAIR / PT)        // 126
#define TOTAL_TILES (BB * TILES_PER_B)  // 16128
#define K2_BLOCKS 2016                  // 8064 waves, 2 tiles each

typedef __attribute__((ext_vector_type(8))) short bf16x8;   // 8 bf16 = 4 VGPRs
typedef __attribute__((ext_vector_type(4))) float f32x4;    // MFMA C/D

// tanh-approx GELU via HW transcendentals (~10 VALU insts vs ~80 for erff).
// max |gelu_tanh - gelu_exact| ~ 5e-4; propagated output error ~1e-3,
// negligible vs bf16-MFMA rounding (1.6e-2) and threshold (5.1e-2).
__device__ __forceinline__ float gelu_fast(float x) {
    const float x2 = x * x;
    const float p = fmaf(0.044715f * x2, x, x);        // x + 0.044715 x^3
    // tanh(c*p), c=sqrt(2/pi): exp2(2*c*log2(e)*p) -> 2.3022150322f
    const float z = __builtin_amdgcn_exp2f(2.3022150322f * p);
    const float r = __builtin_amdgcn_rcpf(z + 1.0f);
    const float th = fmaf(-2.0f, r, 1.0f);             // tanh
    const float hx = 0.5f * x;
    return fmaf(hx, th, hx);                           // 0.5x(1+tanh)
}

// RNE float -> bf16 bits (values finite; no NaN handling needed)
__device__ __forceinline__ unsigned short f2bf(float x) {
    union { float f; unsigned u; } c; c.f = x;
    unsigned r = c.u + 0x7fffu + ((c.u >> 16) & 1u);
    return (unsigned short)(r >> 16);
}

// t -> (i, j), i < j, t = j(j-1)/2 + i
__device__ __forceinline__ void pair_decode(int t, int& i, int& j) {
    int jj = (int)((1.0f + sqrtf(1.0f + 8.0f * (float)t)) * 0.5f);
    if (jj * (jj - 1) / 2 > t) --jj;
    if (jj * (jj + 1) / 2 <= t) ++jj;
    i = t - jj * (jj - 1) / 2;
    j = jj;
}

// ---------------------------------------------------------------------------
// Kernel 1: e = pos_table[pos] + aa_table[aa];  u = e @ W1[:64], v = e @ W1[64:]
// W1 (32 KB) staged in block LDS; 2 tokens per wave (8/block) halves staging
// traffic vs round 3. First 16 blocks also produce W2T (bf16, transposed) --
// the former k0 launch folded in. Zeroes the output diagonal.
// Grid = 1024 blocks x 256.
// ---------------------------------------------------------------------------
__global__ __launch_bounds__(256) void k_embed_uv(
    const int* __restrict__ positions, const int* __restrict__ amino,
    const float* __restrict__ pos_table, const float* __restrict__ aa_table,
    const float* __restrict__ W1, const float* __restrict__ W2,
    float* __restrict__ u, float* __restrict__ v,
    unsigned short* __restrict__ w2t, float* __restrict__ out)
{
    __shared__ __align__(16) float w1s[2 * DD * DD];   // 32 KB, [k][out] layout
    __shared__ __align__(16) float es[4][DD];
    const int wave = threadIdx.x >> 6;
    const int lane = threadIdx.x & 63;

    // cooperative W1 load: 2048 float4 over 256 threads
    {
        const float4* W14 = (const float4*)W1;
        float4* w1s4 = (float4*)w1s;
#pragma unroll
        for (int it = 0; it < 8; ++it)
            w1s4[it * 256 + threadIdx.x] = W14[it * 256 + threadIdx.x];
    }
    // folded w2t prep (4096 elems over first 16 blocks)
    if (blockIdx.x < 16) {
        const int n = blockIdx.x * 256 + threadIdx.x;
        w2t[(n & 63) * DD + (n >> 6)] = f2bf(W2[n]);
    }
    __syncthreads();

#pragma unroll
    for (int it = 0; it < 2; ++it) {
        const int idx = blockIdx.x * 8 + wave * 2 + it;   // b*M + m
        int p = positions[idx];
        p = p < 0 ? 0 : (p > PP - 1 ? PP - 1 : p);
        int a = amino[idx];
        a = a < 0 ? 0 : (a > AN - 1 ? AN - 1 : a);

        const float e = pos_table[p * DD + lane] + aa_table[a * DD + lane];
        es[wave][lane] = e;
        asm volatile("s_waitcnt lgkmcnt(0)" ::: "memory");  // wave-local visibility

        float uacc = 0.0f, vacc = 0.0f;
#pragma unroll
        for (int k = 0; k < DD; ++k) {
            const float ek = es[wave][k];                    // broadcast read
            uacc = fmaf(ek, w1s[k * DD + lane], uacc);       // rows 0..63
            vacc = fmaf(ek, w1s[(DD + k) * DD + lane], vacc);// rows 64..127
        }
        u[idx * DD + lane] = uacc;
        v[idx * DD + lane] = vacc;

        if (lane == 0) {
            const int b = idx >> 6, m = idx & 63;
            out[b * MM * MM + m * MM + m] = 0.0f;            // diagonal
        }
        asm volatile("s_waitcnt lgkmcnt(0)" ::: "memory");   // es reuse fence
    }
}

// ---------------------------------------------------------------------------
// Kernel 2: one wave per 16-pair MFMA tile, 2 tiles per wave (grid-stride)
// to amortize the hoisted W2T/bias fragments.
// Layer 1: lane (g = l>>4, r = l&15) computes h1[pair=r][k=kh*32+g*8+e]
//          = gelu(u_i[k] + v_j[k] + b1[k]) directly into its A-fragment.
// Layer 2: 8x mfma_f32_16x16x32_bf16 (2 k-halves x 4 out-col blocks).
// Layer 3: C/D layout col=l&15, row=(l>>4)*4+reg; gelu + W3 dot +
//          shfl_xor(1,2,4,8) reduce over 16-lane col group; mirrored store.
// ---------------------------------------------------------------------------
__global__ __launch_bounds__(256) void k_pair_mfma(
    const float* __restrict__ u, const float* __restrict__ v,
    const unsigned short* __restrict__ w2t,
    const float* __restrict__ b1, const float* __restrict__ b2,
    const float* __restrict__ W3, const float* __restrict__ b3,
    float* __restrict__ out)
{
    const int lane = threadIdx.x & 63;
    const int wave = threadIdx.x >> 6;
    const int r = lane & 15;        // A row = pair-in-tile; also C col = out feature
    const int g = lane >> 4;        // k-group

    // ---- hoisted per-lane constants ----
    // B fragments: lane holds W2[k = kh*32+g*8+e][n = cb*16+r]
    bf16x8 bfr[2][4];
#pragma unroll
    for (int kh = 0; kh < 2; ++kh)
#pragma unroll
        for (int cb = 0; cb < 4; ++cb)
            bfr[kh][cb] = *(const bf16x8*)(w2t + ((cb * 16 + r) * DD + kh * 32 + g * 8));

    // b1 fragment: b1[kh*32 + g*8 + e]
    float b1f[2][8];
#pragma unroll
    for (int kh = 0; kh < 2; ++kh) {
        const float4 lo = *(const float4*)(b1 + kh * 32 + g * 8);
        const float4 hi = *(const float4*)(b1 + kh * 32 + g * 8 + 4);
        b1f[kh][0] = lo.x; b1f[kh][1] = lo.y; b1f[kh][2] = lo.z; b1f[kh][3] = lo.w;
        b1f[kh][4] = hi.x; b1f[kh][5] = hi.y; b1f[kh][6] = hi.z; b1f[kh][7] = hi.w;
    }
    // b2 / W3 fragments: col = cb*16 + r
    float b2f[4], w3f[4];
#pragma unroll
    for (int cb = 0; cb < 4; ++cb) {
        b2f[cb] = b2[cb * 16 + r];
        w3f[cb] = W3[cb * 16 + r];
    }
    const float b3s = b3[0];

    const int gwave = blockIdx.x * 4 + wave;
    const int nw = K2_BLOCKS * 4;                    // 8064 waves, 2 iterations

    for (int tile = gwave; tile < TOTAL_TILES; tile += nw) {
        const int b = tile / TILES_PER_B;
        const int t0 = (tile - b * TILES_PER_B) * PT;

        // ---- layer 1: build A fragments in-register ----
        int i, j;
        pair_decode(t0 + r, i, j);
        const float* __restrict__ up = u + (b * MM + i) * DD;
        const float* __restrict__ vp = v + (b * MM + j) * DD;

        bf16x8 afr[2];
#pragma unroll
        for (int kh = 0; kh < 2; ++kh) {
            const int koff = kh * 32 + g * 8;
            const float4 u0 = *(const float4*)(up + koff);
            const float4 u1 = *(const float4*)(up + koff + 4);
            const float4 v0 = *(const float4*)(vp + koff);
            const float4 v1 = *(const float4*)(vp + koff + 4);
            float x[8];
            x[0] = u0.x + v0.x; x[1] = u0.y + v0.y; x[2] = u0.z + v0.z; x[3] = u0.w + v0.w;
            x[4] = u1.x + v1.x; x[5] = u1.y + v1.y; x[6] = u1.z + v1.z; x[7] = u1.w + v1.w;
#pragma unroll
            for (int e = 0; e < 8; ++e)
                afr[kh][e] = (short)f2bf(gelu_fast(x[e] + b1f[kh][e]));
        }

        // ---- layer 2: 8 MFMAs, accumulate over k-halves ----
        f32x4 acc[4];
#pragma unroll
        for (int cb = 0; cb < 4; ++cb) {
            f32x4 z = {0.0f, 0.0f, 0.0f, 0.0f};
            z = __builtin_amdgcn_mfma_f32_16x16x32_bf16(afr[0], bfr[0][cb], z, 0, 0, 0);
            acc[cb] = __builtin_amdgcn_mfma_f32_16x16x32_bf16(afr[1], bfr[1][cb], z, 0, 0, 0);
        }

        // ---- layer 3: gelu, W3 dot, reduce over col group, mirrored store ----
        float part[4];
#pragma unroll
        for (int reg = 0; reg < 4; ++reg) {
            float s = 0.0f;
#pragma unroll
            for (int cb = 0; cb < 4; ++cb)
                s = fmaf(gelu_fast(acc[cb][reg] + b2f[cb]), w3f[cb], s);
            // sum over the 16 lanes sharing this g (cols 0..15 of each block)
            s += __shfl_xor(s, 1, 64);
            s += __shfl_xor(s, 2, 64);
            s += __shfl_xor(s, 4, 64);
            s += __shfl_xor(s, 8, 64);
            part[reg] = s;
        }

        if (r == 0) {                      // 4 active lanes (one per g)
            float* __restrict__ ob = out + b * (MM * MM);
#pragma unroll
            for (int reg = 0; reg < 4; ++reg) {
                const int p = g * 4 + reg;               // C row = pair index
                int i2, j2;
                pair_decode(t0 + p, i2, j2);
                const float sc = part[reg] + b3s;
                ob[i2 * MM + j2] = sc;
                ob[j2 * MM + i2] = sc;
            }
        }
    }
}

extern "C" void kernel_launch(void* const* d_in, const int* in_sizes, int n_in,
                              void* d_out, int out_size, void* d_ws, size_t ws_size,
                              hipStream_t stream) {
    const int*   positions = (const int*)  d_in[0];
    const int*   amino     = (const int*)  d_in[1];
    const float* pos_table = (const float*)d_in[2];
    const float* aa_table  = (const float*)d_in[3];
    const float* W1        = (const float*)d_in[4];
    const float* b1        = (const float*)d_in[5];
    const float* W2        = (const float*)d_in[6];
    const float* b2        = (const float*)d_in[7];
    const float* W3        = (const float*)d_in[8];
    const float* b3        = (const float*)d_in[9];
    float* out = (float*)d_out;

    float* u = (float*)d_ws;                              // [B*M, 64]  (2 MB)
    float* v = u + (size_t)BB * MM * DD;                  // [B*M, 64]  (2 MB)
    unsigned short* w2t = (unsigned short*)(v + (size_t)BB * MM * DD);  // 8 KB bf16

    // K1: 8192 tokens, 2/wave -> 1024 blocks of 4 waves (+ folded w2t prep)
    k_embed_uv<<<1024, 256, 0, stream>>>(positions, amino, pos_table, aa_table,
                                         W1, W2, u, v, w2t, out);
    // K2: 16128 tiles -> 2016 blocks of 4 waves, 2 tiles per wave
    k_pair_mfma<<<K2_BLOCKS, 256, 0, stream>>>(u, v, w2t, b1, b2, W3, b3, out);
}

// Round 5
// 41.187 us; speedup vs baseline: 44.0719x; 1.0528x over previous
//
#include <hip/hip_runtime.h>
#include <cmath>

// Problem constants
#define BB 128
#define MM 64
#define DD 64
#define PP 1024
#define AN 21
#define NPAIR 2016            // M*(M-1)/2
#define PT 16                 // pairs per wave-tile = MFMA M dim
#define TILES_PER_B (NPAIR / PT)        // 126
#define TOTAL_TILES (BB * TILES_PER_B)  // 16128
#define K2_BLOCKS 2016                  // 8064 waves x 2 consecutive tiles
#define W1P 68                          // padded LDS row stride (bank-spread)

typedef __attribute__((ext_vector_type(8))) short bf16x8;   // 8 bf16 = 4 VGPRs
typedef __attribute__((ext_vector_type(4))) float f32x4;    // MFMA C/D

// tanh-approx GELU via HW transcendentals (~10 VALU insts vs ~80 for erff).
// max |gelu_tanh - gelu_exact| ~ 5e-4 -> output error ~1e-3, negligible vs
// bf16-MFMA rounding (1.6e-2) and threshold (5.1e-2).
__device__ __forceinline__ float gelu_fast(float x) {
    const float x2 = x * x;
    const float p = fmaf(0.044715f * x2, x, x);        // x + 0.044715 x^3
    const float z = __builtin_amdgcn_exp2f(2.3022150322f * p);  // exp(2c*p)
    const float r = __builtin_amdgcn_rcpf(z + 1.0f);
    const float th = fmaf(-2.0f, r, 1.0f);             // tanh(c*p)
    const float hx = 0.5f * x;
    return fmaf(hx, th, hx);                           // 0.5x(1+tanh)
}

// RNE float -> bf16 bits (values finite)
__device__ __forceinline__ unsigned short f2bf(float x) {
    union { float f; unsigned u; } c; c.f = x;
    unsigned r = c.u + 0x7fffu + ((c.u >> 16) & 1u);
    return (unsigned short)(r >> 16);
}

// t -> (i, j), i < j, t = j(j-1)/2 + i
__device__ __forceinline__ void pair_decode(int t, int& i, int& j) {
    int jj = (int)((1.0f + sqrtf(1.0f + 8.0f * (float)t)) * 0.5f);
    if (jj * (jj - 1) / 2 > t) --jj;
    if (jj * (jj + 1) / 2 <= t) ++jj;
    i = t - jj * (jj - 1) / 2;
    j = jj;
}

// ---------------------------------------------------------------------------
// Kernel 1: u = e @ W1[:64] + b1, v = e @ W1[64:], e = pos_tab[p] + aa_tab[a].
// W1 staged TRANSPOSED in LDS: w1u[out][k], w1v[out][k], row stride 68 floats
// (pad -> bank (4*lane+k)%32, conflict-free float4 reads; unpadded 64 would
// put all 64 lanes on one bank group). Lane = out feature; per token:
// 32 lane-private ds_read_b128 + 16 broadcast b128 vs round-4's 192 scalar.
// b1 folded into u here (exact f32) so k2 drops it entirely.
// 512 blocks x 256 thr; 16 tokens/block (4/wave). First 16 blocks also emit
// W2T (bf16 transposed). Zeroes the output diagonal.
// ---------------------------------------------------------------------------
__global__ __launch_bounds__(256) void k_embed_uv(
    const int* __restrict__ positions, const int* __restrict__ amino,
    const float* __restrict__ pos_table, const float* __restrict__ aa_table,
    const float* __restrict__ W1, const float* __restrict__ W2,
    const float* __restrict__ b1,
    float* __restrict__ u, float* __restrict__ v,
    unsigned short* __restrict__ w2t, float* __restrict__ out)
{
    __shared__ __align__(16) float w1u[DD][W1P];   // W1[k][out], k<64  -> [out][k]
    __shared__ __align__(16) float w1v[DD][W1P];   // W1[64+k][out]     -> [out][k]
    __shared__ __align__(16) float es[4][DD];
    const int wave = threadIdx.x >> 6;
    const int lane = threadIdx.x & 63;

    // cooperative W1 load + transpose: 2048 float4 over 256 threads
    {
        const float4* W14 = (const float4*)W1;
#pragma unroll
        for (int it = 0; it < 8; ++it) {
            const int n = it * 256 + threadIdx.x;     // f4 index
            const int k = n >> 4;                     // W1 row (input dim)
            const int c4 = (n & 15) << 2;             // out base
            const float4 w = W14[n];
            if (k < DD) {
                w1u[c4 + 0][k] = w.x; w1u[c4 + 1][k] = w.y;
                w1u[c4 + 2][k] = w.z; w1u[c4 + 3][k] = w.w;
            } else {
                w1v[c4 + 0][k - DD] = w.x; w1v[c4 + 1][k - DD] = w.y;
                w1v[c4 + 2][k - DD] = w.z; w1v[c4 + 3][k - DD] = w.w;
            }
        }
    }
    // folded w2t prep (4096 elems over first 16 blocks)
    if (blockIdx.x < 16) {
        const int n = blockIdx.x * 256 + threadIdx.x;
        w2t[(n & 63) * DD + (n >> 6)] = f2bf(W2[n]);
    }
    const float b1l = b1[lane];
    __syncthreads();

#pragma unroll
    for (int tt = 0; tt < 4; ++tt) {
        const int idx = blockIdx.x * 16 + wave * 4 + tt;   // b*M + m
        int p = positions[idx];
        p = p < 0 ? 0 : (p > PP - 1 ? PP - 1 : p);
        int a = amino[idx];
        a = a < 0 ? 0 : (a > AN - 1 ? AN - 1 : a);

        const float e = pos_table[p * DD + lane] + aa_table[a * DD + lane];
        asm volatile("s_waitcnt lgkmcnt(0)" ::: "memory");  // prior es reads done
        es[wave][lane] = e;
        asm volatile("s_waitcnt lgkmcnt(0)" ::: "memory");  // write visible (wave-local)

        float uacc = 0.0f, vacc = 0.0f;
#pragma unroll
        for (int k4 = 0; k4 < DD / 4; ++k4) {
            const float4 ek = *(const float4*)&es[wave][k4 * 4];      // broadcast
            const float4 wu = *(const float4*)&w1u[lane][k4 * 4];     // private row
            const float4 wv = *(const float4*)&w1v[lane][k4 * 4];
            uacc = fmaf(ek.x, wu.x, uacc); uacc = fmaf(ek.y, wu.y, uacc);
            uacc = fmaf(ek.z, wu.z, uacc); uacc = fmaf(ek.w, wu.w, uacc);
            vacc = fmaf(ek.x, wv.x, vacc); vacc = fmaf(ek.y, wv.y, vacc);
            vacc = fmaf(ek.z, wv.z, vacc); vacc = fmaf(ek.w, wv.w, vacc);
        }
        u[idx * DD + lane] = uacc + b1l;   // b1 folded in (exact f32)
        v[idx * DD + lane] = vacc;

        if (lane == 0) {
            const int b = idx >> 6, m = idx & 63;
            out[b * MM * MM + m * MM + m] = 0.0f;            // diagonal
        }
    }
}

// ---------------------------------------------------------------------------
// Kernel 2: 2 consecutive 16-pair MFMA tiles per wave (u/v L1/L2 locality).
// Layer 1: lane (g=l>>4, r=l&15) computes h1[pair=r][k=kh*32+g*8+e]
//          = gelu(u'_i[k] + v_j[k]) in-register (b1 already in u').
// Layer 2: 8x mfma_f32_16x16x32_bf16 (2 k-halves x 4 out-col blocks).
// Layer 3: C/D layout col=l&15, row=(l>>4)*4+reg; gelu + W3 dot +
//          shfl_xor(1,2,4,8) reduce over 16-lane col group; mirrored store.
// ---------------------------------------------------------------------------
__global__ __launch_bounds__(256) void k_pair_mfma(
    const float* __restrict__ u, const float* __restrict__ v,
    const unsigned short* __restrict__ w2t,
    const float* __restrict__ b2, const float* __restrict__ W3,
    const float* __restrict__ b3, float* __restrict__ out)
{
    const int lane = threadIdx.x & 63;
    const int wave = threadIdx.x >> 6;
    const int r = lane & 15;        // A row = pair-in-tile; also C col = out feature
    const int g = lane >> 4;        // k-group

    // ---- hoisted per-lane constants ----
    // B fragments: lane holds W2[k = kh*32+g*8+e][n = cb*16+r]
    bf16x8 bfr[2][4];
#pragma unroll
    for (int kh = 0; kh < 2; ++kh)
#pragma unroll
        for (int cb = 0; cb < 4; ++cb)
            bfr[kh][cb] = *(const bf16x8*)(w2t + ((cb * 16 + r) * DD + kh * 32 + g * 8));

    // b2 / W3 fragments: col = cb*16 + r
    float b2f[4], w3f[4];
#pragma unroll
    for (int cb = 0; cb < 4; ++cb) {
        b2f[cb] = b2[cb * 16 + r];
        w3f[cb] = W3[cb * 16 + r];
    }
    const float b3s = b3[0];

    const int gwave = blockIdx.x * 4 + wave;   // 8064 waves, tiles 2w, 2w+1

#pragma unroll
    for (int it = 0; it < 2; ++it) {
        const int tile = gwave * 2 + it;
        const int b = tile / TILES_PER_B;
        const int t0 = (tile - b * TILES_PER_B) * PT;

        // ---- layer 1: build A fragments in-register ----
        int i, j;
        pair_decode(t0 + r, i, j);
        const float* __restrict__ up = u + (b * MM + i) * DD;
        const float* __restrict__ vp = v + (b * MM + j) * DD;

        bf16x8 afr[2];
#pragma unroll
        for (int kh = 0; kh < 2; ++kh) {
            const int koff = kh * 32 + g * 8;
            const float4 u0 = *(const float4*)(up + koff);
            const float4 u1 = *(const float4*)(up + koff + 4);
            const float4 v0 = *(const float4*)(vp + koff);
            const float4 v1 = *(const float4*)(vp + koff + 4);
            float x[8];
            x[0] = u0.x + v0.x; x[1] = u0.y + v0.y; x[2] = u0.z + v0.z; x[3] = u0.w + v0.w;
            x[4] = u1.x + v1.x; x[5] = u1.y + v1.y; x[6] = u1.z + v1.z; x[7] = u1.w + v1.w;
#pragma unroll
            for (int e = 0; e < 8; ++e)
                afr[kh][e] = (short)f2bf(gelu_fast(x[e]));
        }

        // ---- layer 2: 8 MFMAs, accumulate over k-halves ----
        f32x4 acc[4];
#pragma unroll
        for (int cb = 0; cb < 4; ++cb) {
            f32x4 z = {0.0f, 0.0f, 0.0f, 0.0f};
            z = __builtin_amdgcn_mfma_f32_16x16x32_bf16(afr[0], bfr[0][cb], z, 0, 0, 0);
            acc[cb] = __builtin_amdgcn_mfma_f32_16x16x32_bf16(afr[1], bfr[1][cb], z, 0, 0, 0);
        }

        // ---- layer 3: gelu, W3 dot, reduce over col group, mirrored store ----
        float part[4];
#pragma unroll
        for (int reg = 0; reg < 4; ++reg) {
            float s = 0.0f;
#pragma unroll
            for (int cb = 0; cb < 4; ++cb)
                s = fmaf(gelu_fast(acc[cb][reg] + b2f[cb]), w3f[cb], s);
            s += __shfl_xor(s, 1, 64);
            s += __shfl_xor(s, 2, 64);
            s += __shfl_xor(s, 4, 64);
            s += __shfl_xor(s, 8, 64);
            part[reg] = s;
        }

        if (r == 0) {                      // 4 active lanes (one per g)
            float* __restrict__ ob = out + b * (MM * MM);
#pragma unroll
            for (int reg = 0; reg < 4; ++reg) {
                const int p = g * 4 + reg;               // C row = pair index
                int i2, j2;
                pair_decode(t0 + p, i2, j2);
                const float sc = part[reg] + b3s;
                ob[i2 * MM + j2] = sc;
                ob[j2 * MM + i2] = sc;
            }
        }
    }
}

extern "C" void kernel_launch(void* const* d_in, const int* in_sizes, int n_in,
                              void* d_out, int out_size, void* d_ws, size_t ws_size,
                              hipStream_t stream) {
    const int*   positions = (const int*)  d_in[0];
    const int*   amino     = (const int*)  d_in[1];
    const float* pos_table = (const float*)d_in[2];
    const float* aa_table  = (const float*)d_in[3];
    const float* W1        = (const float*)d_in[4];
    const float* b1        = (const float*)d_in[5];
    const float* W2        = (const float*)d_in[6];
    const float* b2        = (const float*)d_in[7];
    const float* W3        = (const float*)d_in[8];
    const float* b3        = (const float*)d_in[9];
    float* out = (float*)d_out;

    float* u = (float*)d_ws;                              // [B*M, 64] (2 MB), b1 folded
    float* v = u + (size_t)BB * MM * DD;                  // [B*M, 64] (2 MB)
    unsigned short* w2t = (unsigned short*)(v + (size_t)BB * MM * DD);  // 8 KB bf16

    // K1: 8192 tokens, 16/block -> 512 blocks (+ folded w2t prep)
    k_embed_uv<<<512, 256, 0, stream>>>(positions, amino, pos_table, aa_table,
                                        W1, W2, b1, u, v, w2t, out);
    // K2: 16128 tiles -> 2016 blocks of 4 waves, 2 consecutive tiles per wave
    k_pair_mfma<<<K2_BLOCKS, 256, 0, stream>>>(u, v, w2t, b2, W3, b3, out);
}

// Round 6
// 34.478 us; speedup vs baseline: 52.6475x; 1.1946x over previous
//
#include <hip/hip_runtime.h>
#include <hip/hip_bf16.h>
#include <cmath>

// Problem constants
#define BB 128
#define MM 64
#define DD 64
#define PP 1024
#define AN 21
#define W1P 68                          // padded LDS row stride (bank-spread)
#define UVP 68                          // padded u/v LDS row stride in k2

typedef __attribute__((ext_vector_type(8))) short bf16x8;   // 8 bf16 = 4 VGPRs
typedef __attribute__((ext_vector_type(4))) float f32x4;    // MFMA C/D

// tanh-approx GELU via HW transcendentals (~10 VALU insts vs ~80 for erff).
// max |gelu_tanh - gelu_exact| ~ 5e-4 -> output error ~1e-3, negligible vs
// bf16-MFMA rounding (1.6e-2) and threshold (5.1e-2).
__device__ __forceinline__ float gelu_fast(float x) {
    const float x2 = x * x;
    const float p = fmaf(0.044715f * x2, x, x);        // x + 0.044715 x^3
    const float z = __builtin_amdgcn_exp2f(2.3022150322f * p);  // exp(2c*p)
    const float r = __builtin_amdgcn_rcpf(z + 1.0f);
    const float th = fmaf(-2.0f, r, 1.0f);             // tanh(c*p)
    const float hx = 0.5f * x;
    return fmaf(hx, th, hx);                           // 0.5x(1+tanh)
}

// RNE float -> bf16 bits (values finite)
__device__ __forceinline__ unsigned short f2bf(float x) {
    union { float f; unsigned u; } c; c.f = x;
    unsigned r = c.u + 0x7fffu + ((c.u >> 16) & 1u);
    return (unsigned short)(r >> 16);
}

// pack 2 floats -> 1 u32 of 2 bf16 (should emit v_cvt_pk_bf16_f32)
__device__ __forceinline__ unsigned pk2bf(float lo, float hi) {
    __hip_bfloat162 t = __float22bfloat162_rn(make_float2(lo, hi));
    unsigned u; __builtin_memcpy(&u, &t, 4);
    return u;
}

// butterfly sum over each 16-lane row via DPP (xor 1,2,4,8); all lanes get sum
__device__ __forceinline__ float row_sum16(float x) {
    int t;
    t = __builtin_amdgcn_update_dpp(0, __float_as_int(x), 0xB1, 0xF, 0xF, true); // quad_perm [1,0,3,2] = xor1
    x += __int_as_float(t);
    t = __builtin_amdgcn_update_dpp(0, __float_as_int(x), 0x4E, 0xF, 0xF, true); // quad_perm [2,3,0,1] = xor2
    x += __int_as_float(t);
    t = __builtin_amdgcn_update_dpp(0, __float_as_int(x), 0x141, 0xF, 0xF, true); // row_half_mirror = xor4
    x += __int_as_float(t);
    t = __builtin_amdgcn_update_dpp(0, __float_as_int(x), 0x140, 0xF, 0xF, true); // row_mirror = xor8
    x += __int_as_float(t);
    return x;
}

// ---------------------------------------------------------------------------
// Kernel 1: u = e @ W1[:64] + b1, v = e @ W1[64:], e = pos_tab[p] + aa_tab[a].
// W1 staged TRANSPOSED+padded in LDS; lane = out feature reads private rows
// as float4 (conflict-free). b1 folded into u (exact f32). First 16 blocks
// emit W2T (bf16 transposed). Zeroes the output diagonal. 512 blocks x 256.
// ---------------------------------------------------------------------------
__global__ __launch_bounds__(256) void k_embed_uv(
    const int* __restrict__ positions, const int* __restrict__ amino,
    const float* __restrict__ pos_table, const float* __restrict__ aa_table,
    const float* __restrict__ W1, const float* __restrict__ W2,
    const float* __restrict__ b1,
    float* __restrict__ u, float* __restrict__ v,
    unsigned short* __restrict__ w2t, float* __restrict__ out)
{
    __shared__ __align__(16) float w1u[DD][W1P];
    __shared__ __align__(16) float w1v[DD][W1P];
    __shared__ __align__(16) float es[4][DD];
    const int wave = threadIdx.x >> 6;
    const int lane = threadIdx.x & 63;

    // cooperative W1 load + transpose: 2048 float4 over 256 threads
    {
        const float4* W14 = (const float4*)W1;
#pragma unroll
        for (int it = 0; it < 8; ++it) {
            const int n = it * 256 + threadIdx.x;     // f4 index
            const int k = n >> 4;                     // W1 row (input dim)
            const int c4 = (n & 15) << 2;             // out base
            const float4 w = W14[n];
            if (k < DD) {
                w1u[c4 + 0][k] = w.x; w1u[c4 + 1][k] = w.y;
                w1u[c4 + 2][k] = w.z; w1u[c4 + 3][k] = w.w;
            } else {
                w1v[c4 + 0][k - DD] = w.x; w1v[c4 + 1][k - DD] = w.y;
                w1v[c4 + 2][k - DD] = w.z; w1v[c4 + 3][k - DD] = w.w;
            }
        }
    }
    // folded w2t prep (4096 elems over first 16 blocks)
    if (blockIdx.x < 16) {
        const int n = blockIdx.x * 256 + threadIdx.x;
        w2t[(n & 63) * DD + (n >> 6)] = f2bf(W2[n]);
    }
    const float b1l = b1[lane];
    __syncthreads();

#pragma unroll
    for (int tt = 0; tt < 4; ++tt) {
        const int idx = blockIdx.x * 16 + wave * 4 + tt;   // b*M + m
        int p = positions[idx];
        p = p < 0 ? 0 : (p > PP - 1 ? PP - 1 : p);
        int a = amino[idx];
        a = a < 0 ? 0 : (a > AN - 1 ? AN - 1 : a);

        const float e = pos_table[p * DD + lane] + aa_table[a * DD + lane];
        asm volatile("s_waitcnt lgkmcnt(0)" ::: "memory");  // prior es reads done
        es[wave][lane] = e;
        asm volatile("s_waitcnt lgkmcnt(0)" ::: "memory");  // write visible (wave-local)

        float uacc = 0.0f, vacc = 0.0f;
#pragma unroll
        for (int k4 = 0; k4 < DD / 4; ++k4) {
            const float4 ek = *(const float4*)&es[wave][k4 * 4];      // broadcast
            const float4 wu = *(const float4*)&w1u[lane][k4 * 4];     // private row
            const float4 wv = *(const float4*)&w1v[lane][k4 * 4];
            uacc = fmaf(ek.x, wu.x, uacc); uacc = fmaf(ek.y, wu.y, uacc);
            uacc = fmaf(ek.z, wu.z, uacc); uacc = fmaf(ek.w, wu.w, uacc);
            vacc = fmaf(ek.x, wv.x, vacc); vacc = fmaf(ek.y, wv.y, vacc);
            vacc = fmaf(ek.z, wv.z, vacc); vacc = fmaf(ek.w, wv.w, vacc);
        }
        u[idx * DD + lane] = uacc + b1l;   // b1 folded in (exact f32)
        v[idx * DD + lane] = vacc;

        if (lane == 0) {
            const int b = idx >> 6, m = idx & 63;
            out[b * MM * MM + m * MM + m] = 0.0f;            // diagonal
        }
    }
}

// ---------------------------------------------------------------------------
// Kernel 2: workgroup = one (batch b, ib, jb) 16x16 block of the pair plane.
// blk 0..5: strictly-upper blocks (ib<jb); blk 6..9: diagonal (store p<pj only;
// lower-half results are wrong-order and masked). Grid (10, 128).
// Stage u rows [ib*16..+15] and v rows [jb*16..+15] COALESCED into LDS
// (padded stride 68 -> 2 lanes/bank on the row-scattered ds_read_b128, free),
// replacing round-5's scattered global gathers (~32 cache lines per load
// inst, L1-pipe-bound). Wave w, iter tt -> column pj = tt*4+w; A-row = local
// pair p (16 rows of u), v row broadcast.
// Layer 2: 8x mfma_f32_16x16x32_bf16. Layer 3: gelu + W3 dot + DPP xor-
// butterfly sum over the 16-lane row; lanes r<4 store pair g*4+r mirrored.
// ---------------------------------------------------------------------------
__global__ __launch_bounds__(256) void k_pair_mfma(
    const float* __restrict__ u, const float* __restrict__ v,
    const unsigned short* __restrict__ w2t,
    const float* __restrict__ b2, const float* __restrict__ W3,
    const float* __restrict__ b3, float* __restrict__ out)
{
    __shared__ __align__(16) float us[16][UVP];
    __shared__ __align__(16) float vs[16][UVP];
    const int lane = threadIdx.x & 63;
    const int wave = threadIdx.x >> 6;
    const int r = lane & 15;        // A row (build) / C col (output)
    const int g = lane >> 4;

    const int blk = blockIdx.x;     // 0..9
    const int b   = blockIdx.y;     // 0..127
    // packed (ib, jb) tables, 3 bits each: blocks {01,02,03,12,13,23, 00,11,22,33}
    const int ib = (0x1A211200u >> (3 * blk)) & 7;
    const int jb = (0x1A21B4D1u >> (3 * blk)) & 7;
    const bool diag = (blk >= 6);

    // coalesced stage: 16 rows x 64 floats each of u and v
    {
        const int row = threadIdx.x >> 4;      // 0..15
        const int q   = threadIdx.x & 15;      // float4 index in row
        const float4 uq = *(const float4*)(u + ((b * MM + ib * 16 + row) * DD) + q * 4);
        const float4 vq = *(const float4*)(v + ((b * MM + jb * 16 + row) * DD) + q * 4);
        *(float4*)&us[row][q * 4] = uq;
        *(float4*)&vs[row][q * 4] = vq;
    }

    // hoisted per-lane constants
    bf16x8 bfr[2][4];               // B frag: W2[k=kh*32+g*8+e][n=cb*16+r]
#pragma unroll
    for (int kh = 0; kh < 2; ++kh)
#pragma unroll
        for (int cb = 0; cb < 4; ++cb)
            bfr[kh][cb] = *(const bf16x8*)(w2t + ((cb * 16 + r) * DD + kh * 32 + g * 8));
    float b2f[4], w3f[4];
#pragma unroll
    for (int cb = 0; cb < 4; ++cb) {
        b2f[cb] = b2[cb * 16 + r];
        w3f[cb] = W3[cb * 16 + r];
    }
    const float b3s = b3[0];

    __syncthreads();

    float* __restrict__ ob = out + b * (MM * MM);
    const int i0 = ib * 16;

#pragma unroll
    for (int tt = 0; tt < 4; ++tt) {
        const int pj = tt * 4 + wave;            // 0..15, column within block
        const int jg = jb * 16 + pj;             // global j

        // ---- layer 1: A frags from LDS (u rows scattered, v row broadcast) ----
        bf16x8 afr[2];
#pragma unroll
        for (int kh = 0; kh < 2; ++kh) {
            const int koff = kh * 32 + g * 8;
            const float4 u0 = *(const float4*)&us[r][koff];
            const float4 u1 = *(const float4*)&us[r][koff + 4];
            const float4 v0 = *(const float4*)&vs[pj][koff];
            const float4 v1 = *(const float4*)&vs[pj][koff + 4];
            float x[8];
            x[0] = u0.x + v0.x; x[1] = u0.y + v0.y; x[2] = u0.z + v0.z; x[3] = u0.w + v0.w;
            x[4] = u1.x + v1.x; x[5] = u1.y + v1.y; x[6] = u1.z + v1.z; x[7] = u1.w + v1.w;
            unsigned w0 = pk2bf(gelu_fast(x[0]), gelu_fast(x[1]));
            unsigned w1 = pk2bf(gelu_fast(x[2]), gelu_fast(x[3]));
            unsigned w2 = pk2bf(gelu_fast(x[4]), gelu_fast(x[5]));
            unsigned w3 = pk2bf(gelu_fast(x[6]), gelu_fast(x[7]));
            union { bf16x8 v8; unsigned u4[4]; } cvt;
            cvt.u4[0] = w0; cvt.u4[1] = w1; cvt.u4[2] = w2; cvt.u4[3] = w3;
            afr[kh] = cvt.v8;
        }

        // ---- layer 2: 8 MFMAs ----
        f32x4 acc[4];
#pragma unroll
        for (int cb = 0; cb < 4; ++cb) {
            f32x4 z = {0.0f, 0.0f, 0.0f, 0.0f};
            z = __builtin_amdgcn_mfma_f32_16x16x32_bf16(afr[0], bfr[0][cb], z, 0, 0, 0);
            acc[cb] = __builtin_amdgcn_mfma_f32_16x16x32_bf16(afr[1], bfr[1][cb], z, 0, 0, 0);
        }

        // ---- layer 3: gelu + W3 dot, DPP row-sum; lane holds pairs g*4+reg ----
        float s0, s1, s2, s3;
        {
            float a0 = 0, a1 = 0, a2 = 0, a3 = 0;
#pragma unroll
            for (int cb = 0; cb < 4; ++cb) {
                a0 = fmaf(gelu_fast(acc[cb][0] + b2f[cb]), w3f[cb], a0);
                a1 = fmaf(gelu_fast(acc[cb][1] + b2f[cb]), w3f[cb], a1);
                a2 = fmaf(gelu_fast(acc[cb][2] + b2f[cb]), w3f[cb], a2);
                a3 = fmaf(gelu_fast(acc[cb][3] + b2f[cb]), w3f[cb], a3);
            }
            s0 = row_sum16(a0) + b3s;
            s1 = row_sum16(a1) + b3s;
            s2 = row_sum16(a2) + b3s;
            s3 = row_sum16(a3) + b3s;
        }

        if (r < 4) {
            const int p = g * 4 + r;                 // local pair (C row)
            if (!diag || p < pj) {
                const float sc = (r == 0) ? s0 : (r == 1) ? s1 : (r == 2) ? s2 : s3;
                const int ig = i0 + p;
                ob[ig * MM + jg] = sc;               // column (scattered)
                ob[jg * MM + ig] = sc;               // mirror row (coalesced)
            }
        }
    }
}

extern "C" void kernel_launch(void* const* d_in, const int* in_sizes, int n_in,
                              void* d_out, int out_size, void* d_ws, size_t ws_size,
                              hipStream_t stream) {
    const int*   positions = (const int*)  d_in[0];
    const int*   amino     = (const int*)  d_in[1];
    const float* pos_table = (const float*)d_in[2];
    const float* aa_table  = (const float*)d_in[3];
    const float* W1        = (const float*)d_in[4];
    const float* b1        = (const float*)d_in[5];
    const float* W2        = (const float*)d_in[6];
    const float* b2        = (const float*)d_in[7];
    const float* W3        = (const float*)d_in[8];
    const float* b3        = (const float*)d_in[9];
    float* out = (float*)d_out;

    float* u = (float*)d_ws;                              // [B*M, 64] (2 MB), b1 folded
    float* v = u + (size_t)BB * MM * DD;                  // [B*M, 64] (2 MB)
    unsigned short* w2t = (unsigned short*)(v + (size_t)BB * MM * DD);  // 8 KB bf16

    // K1: 8192 tokens, 16/block -> 512 blocks (+ folded w2t prep)
    k_embed_uv<<<512, 256, 0, stream>>>(positions, amino, pos_table, aa_table,
                                        W1, W2, b1, u, v, w2t, out);
    // K2: (10 pair-blocks) x (128 batches), 256 threads each
    k_pair_mfma<<<dim3(10, 128), 256, 0, stream>>>(u, v, w2t, b2, W3, b3, out);
}